// Round 7
// baseline (2753.148 us; speedup 1.0000x reference)
//
#include <hip/hip_runtime.h>
#include <hip/hip_bf16.h>
#include <math.h>

// Problem constants
#define B_ 8
#define S_ 32
#define J_ 4
#define L_ 32
#define E_ 500
#define H_ 500
#define NI_ 5000
#define NT_ 48
#define G4_ 2000   // 4*H

#define NB_ 16     // blocks per recurrent gang
#define RPB_ 32    // h indices per block (16*32 = 512 >= 500)
#define TPB_ 1024  // threads: b(8) x ksec(4) x q(32)
#define FPAD_ 32   // flag padding in ints (128 B)

typedef unsigned long long ull;

__device__ __forceinline__ float sigm(float x) { return 1.f / (1.f + expf(-x)); }
__device__ __forceinline__ float seluf(float x) {
    const float sc = 1.0507009873554805f, al = 1.6732632423543772f;
    return x > 0.f ? sc * x : sc * al * (expf(x) - 1.f);
}
// agent-scope ops: bypass L1/L2, coherent at L3; no fences / no wbl2
__device__ __forceinline__ float cohload(const float* p) {
    return __hip_atomic_load(p, __ATOMIC_RELAXED, __HIP_MEMORY_SCOPE_AGENT);
}
__device__ __forceinline__ ull cohload64(const ull* p) {
    return __hip_atomic_load(p, __ATOMIC_RELAXED, __HIP_MEMORY_SCOPE_AGENT);
}
__device__ __forceinline__ void cohstore(float* p, float v) {
    __hip_atomic_store(p, v, __ATOMIC_RELAXED, __HIP_MEMORY_SCOPE_AGENT);
}

// ---------------- zero the flag slots ----------------
__global__ void k_zero(int* p, int n) {
    int i = blockIdx.x * blockDim.x + threadIdx.x;
    if (i < n) __hip_atomic_store(&p[i], 0, __ATOMIC_RELAXED, __HIP_MEMORY_SCOPE_AGENT);
}

// ---------------- embedding gather ----------------
__global__ __launch_bounds__(128) void k_embed(const int* __restrict__ itemv,
                                               const int* __restrict__ histi,
                                               const float* __restrict__ embW,
                                               float* __restrict__ items,
                                               float* __restrict__ histemb) {
    int row = blockIdx.x;
    int id;
    float* dst;
    if (row < 256) { id = itemv[row]; dst = items + (size_t)row * E_; }
    else           { int rr = row - 256; id = histi[rr]; dst = histemb + (size_t)rr * E_; }
    const float4* s = (const float4*)(embW + (size_t)id * E_);
    float4* d = (float4*)dst;
    if (threadIdx.x < 125) d[threadIdx.x] = s[threadIdx.x];
}

// ---------------- generic GEMM: C[M,N] = A[M,K] @ B[N,K]^T + bias[N] ----------------
#define TBM 64
#define TBN 64
#define TBK 16
__global__ __launch_bounds__(256) void k_gemm_bt(const float* __restrict__ A,
                                                 const float* __restrict__ Bm,
                                                 const float* __restrict__ bias,
                                                 float* __restrict__ C,
                                                 int M, int N, int K) {
    __shared__ float As[TBK][TBM + 1];
    __shared__ float Bs[TBK][TBN + 1];
    const int tid = threadIdx.x;
    const int tx = tid & 15, ty = tid >> 4;
    const int row0 = blockIdx.y * TBM, col0 = blockIdx.x * TBN;
    float acc[4][4] = {};
    for (int k0 = 0; k0 < K; k0 += TBK) {
#pragma unroll
        for (int i = 0; i < 4; ++i) {
            int e = tid + i * 256;
            int kk = e & 15, m = e >> 4;
            int gk = k0 + kk;
            float va = 0.f, vb = 0.f;
            int gm = row0 + m, gn = col0 + m;
            if (gk < K) {
                if (gm < M) va = A[(size_t)gm * K + gk];
                if (gn < N) vb = Bm[(size_t)gn * K + gk];
            }
            As[kk][m] = va;
            Bs[kk][m] = vb;
        }
        __syncthreads();
#pragma unroll
        for (int kk = 0; kk < TBK; ++kk) {
            float a[4], bb[4];
#pragma unroll
            for (int i = 0; i < 4; ++i) a[i] = As[kk][ty * 4 + i];
#pragma unroll
            for (int i = 0; i < 4; ++i) bb[i] = Bs[kk][tx * 4 + i];
#pragma unroll
            for (int i = 0; i < 4; ++i)
#pragma unroll
                for (int j = 0; j < 4; ++j) acc[i][j] += a[i] * bb[j];
        }
        __syncthreads();
    }
#pragma unroll
    for (int i = 0; i < 4; ++i) {
        int gm = row0 + ty * 4 + i;
        if (gm >= M) continue;
#pragma unroll
        for (int j = 0; j < 4; ++j) {
            int gn = col0 + tx * 4 + j;
            if (gn < N) C[(size_t)gm * N + gn] = acc[i][j] + (bias ? bias[gn] : 0.f);
        }
    }
}

// ---------------- multi-block batched recurrent kernel (v7) ----------------
// Thread layout: b = tid[0:2], ksec = tid[3:4], q = tid[5:9].
// Each thread: partial dot (4 gates) of h[b][ksec*128..] with Wh rows of
// h-index r0+q. The 4 ksec partials reduce via shfl_xor(8) + shfl_xor(16)
// (ksec lives in lane bits 3-4) -> every lane holds the full z for (q,b).
// Cell state c replicated in the 4 ksec lanes' registers. No z/part LDS.
// Sync: 16 padded flag slots per gang (128B apart) + s_sleep backoff poll.
__global__ __launch_bounds__(TPB_) void k_rec7(
    const float* __restrict__ xwm, const float* __restrict__ Whm,
    const float* __restrict__ xwd, const float* __restrict__ Whd,
    const int* __restrict__ dilidx,
    const float* __restrict__ xwh, const float* __restrict__ Whh,
    float* __restrict__ outm, float* __restrict__ outh,
    float* __restrict__ csg, float* __restrict__ he,
    int* __restrict__ flags) {
    __shared__ __align__(16) float h_s[8][500];
    float* hflat = &h_s[0][0];
    const int tid = threadIdx.x;
    const int gb = blockIdx.x;
    const int role = gb >> 4;           // /NB_: 0 main, 1 dil, 2 hist
    const int blk = gb & (NB_ - 1);
    const int r0 = blk * RPB_;

    const float* Wh   = (role == 0) ? Whm : (role == 1) ? Whd : Whh;
    const float* xw   = (role == 0) ? xwm : (role == 1) ? xwd : xwh;
    const float* exch = (role == 0) ? outm : (role == 1) ? outh : he;
    const int nsteps  = (role == 2) ? 128 : 32;
    const int rstride = (role == 2) ? 128 : S_;
    int* flag = flags + role * NB_ * FPAD_;

    const int b    = tid & 7;
    const int ksec = (tid >> 3) & 3;
    const int q    = tid >> 5;          // 0..31
    const int hi   = r0 + q;
    const int hic  = (hi < 500) ? hi : 499;
    const int kbase = ksec * 128;
    const int n4    = (ksec < 3) ? 32 : 29;   // last section = 116 floats

    const float4* wp0 = (const float4*)(Wh + (size_t)(0 * 500 + hic) * 500 + kbase);
    const float4* wp1 = (const float4*)(Wh + (size_t)(1 * 500 + hic) * 500 + kbase);
    const float4* wp2 = (const float4*)(Wh + (size_t)(2 * 500 + hic) * 500 + kbase);
    const float4* wp3 = (const float4*)(Wh + (size_t)(3 * 500 + hic) * 500 + kbase);

    // staging: threads 0..999 stage one float4 each (2 x uncached b64)
    const int e0  = tid;
    const int bb0 = e0 / 125, k40 = e0 - bb0 * 125;

    float c_reg = 0.f;

    for (int t = 0; t < nsteps; ++t) {
        // xw prefetch (independent of h) -> issue before the poll
        const float* xr = xw + (size_t)(b * nsteps + t) * G4_ + hic;
        float xi = xr[0], xf = xr[500], xg = xr[1000], xo = xr[1500];

        float a0 = 0.f, a1 = 0.f, a2 = 0.f, a3 = 0.f;
        float pc_r = 0.f;
        if (t > 0) {
            // ---- wait for all blocks of this gang to finish step t-1 ----
            if (tid < 64) {
                while (true) {
                    int v = (tid < NB_)
                        ? __hip_atomic_load(&flag[tid * FPAD_], __ATOMIC_RELAXED,
                                            __HIP_MEMORY_SCOPE_AGENT)
                        : 0x7fffffff;
                    if (__all(v >= t)) break;
                    __builtin_amdgcn_s_sleep(2);
                }
            }
            __syncthreads();

            // role-1 prev-cell gather (same addr across ksec lanes -> merged)
            if (role == 1) {
                int it = dilidx[b * S_ + t];
                pc_r = cohload(&csg[((size_t)(b * S_ + it)) * H_ + hic]);
            }

            // ---- batched staging: 2 independent uncached b64 loads -> LDS b128 ----
            if (tid < 1000) {
                int row0 = (role == 1) ? dilidx[bb0 * S_ + t] : (t - 1);
                const ull* p0 = (const ull*)(exch + ((size_t)(bb0 * rstride + row0)) * H_ + k40 * 4);
                ull u0 = cohload64(p0);
                ull u1 = cohload64(p0 + 1);
                union { ull u[2]; float4 f; } uf;
                uf.u[0] = u0; uf.u[1] = u1;
                *(float4*)&hflat[(size_t)e0 * 4] = uf.f;
            }
            __syncthreads();

            // ---- GEMV partials: 4 gates over this thread's 128-k section ----
            const float4* hp = (const float4*)(&h_s[b][kbase]);
#pragma unroll 2
            for (int k4 = 0; k4 < n4; ++k4) {
                float4 hv = hp[k4];
                float4 w0 = wp0[k4], w1 = wp1[k4], w2 = wp2[k4], w3 = wp3[k4];
                a0 += w0.x * hv.x + w0.y * hv.y + w0.z * hv.z + w0.w * hv.w;
                a1 += w1.x * hv.x + w1.y * hv.y + w1.z * hv.z + w1.w * hv.w;
                a2 += w2.x * hv.x + w2.y * hv.y + w2.z * hv.z + w2.w * hv.w;
                a3 += w3.x * hv.x + w3.y * hv.y + w3.z * hv.z + w3.w * hv.w;
            }
        }

        // ---- reduce the 4 ksec partials via lane butterfly (bits 3,4) ----
        a0 += __shfl_xor(a0, 8);  a0 += __shfl_xor(a0, 16);
        a1 += __shfl_xor(a1, 8);  a1 += __shfl_xor(a1, 16);
        a2 += __shfl_xor(a2, 8);  a2 += __shfl_xor(a2, 16);
        a3 += __shfl_xor(a3, 8);  a3 += __shfl_xor(a3, 16);

        float zi = xi + a0, zf = xf + a1, zg = xg + a2, zo = xo + a3;
        float pc = (role == 1) ? pc_r : c_reg;
        float cc = sigm(zf) * pc + sigm(zi) * tanhf(zg);
        float hh = sigm(zo) * tanhf(cc);
        c_reg = cc;    // identical across the 4 ksec lanes

        if (hi < 500) {
            if (role == 0) {
                if (ksec == 0) cohstore(&outm[((size_t)(b * S_ + t)) * H_ + hi], hh);
            } else if (role == 2) {
                if (ksec == 0) cohstore(&he[((size_t)(b * 128 + t)) * H_ + hi], hh);
            } else {
                if (ksec == 0) cohstore(&outh[((size_t)(b * S_ + t)) * H_ + hi], hh);
                if (ksec == 1) cohstore(&csg[((size_t)(b * S_ + t)) * H_ + hi], cc);
            }
        }
        __syncthreads();   // drains vmcnt(0): agent-scope stores complete at L3
        if (tid == 0)
            __hip_atomic_store(&flag[blk * FPAD_], t + 1, __ATOMIC_RELAXED,
                               __HIP_MEMORY_SCOPE_AGENT);
    }
}

// ---------------- masked mean pooling ----------------
__global__ __launch_bounds__(512) void k_pool(const float* __restrict__ outm,
                                              const float* __restrict__ mask,
                                              float* __restrict__ pooled) {
    int b = blockIdx.x, tid = threadIdx.x;
    if (tid >= 500) return;
    float acc = 0.f, den = 0.f;
    for (int s = 0; s < S_; ++s) {
        float mk = mask[b * S_ + s];
        acc += outm[((size_t)(b * S_ + s)) * H_ + tid] * mk;
        den += mk;
    }
    pooled[b * H_ + tid] = acc / den;
}

// ---------------- session rep: sess[b,j,s,:] and avgd[b,j,s] ----------------
__global__ __launch_bounds__(512) void k_sess(const int* __restrict__ seqtim,
                                              const int* __restrict__ itemv,
                                              const int* __restrict__ histt,
                                              const int* __restrict__ histi,
                                              const float* __restrict__ timsim,
                                              const float* __restrict__ poid,
                                              const float* __restrict__ he,
                                              float* __restrict__ sess,
                                              float* __restrict__ avgd) {
    int bi = blockIdx.x;                // B*J*31
    int s = bi % 31;
    int tmpv = bi / 31;
    int j = tmpv & 3, b = tmpv >> 2;
    __shared__ float w[L_];
    __shared__ float pd[L_];
    __shared__ float stats[1];
    int tid = threadIdx.x;
    int st = seqtim[b * S_ + s];
    if (tid < L_) {
        int ht = histt[(b * J_ + j) * L_ + tid];
        w[tid] = timsim[st * NT_ + ht];
    }
    if (tid >= 64 && tid < 64 + L_) {   // parallel poi_dist gather
        int l = tid - 64;
        int iv = itemv[b * S_ + s];
        pd[l] = poid[(size_t)iv * NI_ + histi[(b * J_ + j) * L_ + l]];
    }
    __syncthreads();
    if (tid == 64) {
        float a = 0.f;
        for (int l = 0; l < L_; ++l) a += pd[l];
        avgd[(b * J_ + j) * 31 + s] = a * (1.f / 32.f);
    }
    if (tid == 0) {
        float m = -1e30f;
        for (int l = 0; l < L_; ++l) m = fmaxf(m, w[l]);
        float sm = 0.f;
        for (int l = 0; l < L_; ++l) { float e = expf(w[l] - m); w[l] = e; sm += e; }
        stats[0] = 1.f / sm;
    }
    __syncthreads();
    if (tid < 500) {
        float inv = stats[0];
        float acc = 0.f;
        const float* hp = he + ((size_t)(b * J_ * L_ + j * L_)) * H_ + tid;
        for (int l = 0; l < L_; ++l) acc += w[l] * inv * hp[(size_t)l * H_];
        sess[((size_t)((b * J_ + j) * 31 + s)) * H_ + tid] = acc;
    }
}

// ---------------- attention 1 ----------------
__global__ __launch_bounds__(512) void k_att1(const float* __restrict__ sess,
                                              const float* __restrict__ pooled,
                                              float* __restrict__ att1) {
    int bi = blockIdx.x;   // B*31
    int s = bi % 31, b = bi / 31;
    __shared__ float vec[H_];
    __shared__ float part[512];
    int tid = threadIdx.x;
    if (tid < 500) vec[tid] = pooled[b * H_ + tid];
    __syncthreads();
    int j = tid >> 7, i = tid & 127;
    const float* sp = sess + ((size_t)((b * J_ + j) * 31 + s)) * H_;
    float acc = 0.f;
    for (int h = i; h < H_; h += 128) acc += sp[h] * vec[h];
    part[tid] = acc;
    __syncthreads();
    for (int off = 64; off > 0; off >>= 1) {
        if (i < off) part[tid] += part[tid + off];
        __syncthreads();
    }
    float d0 = part[0], d1 = part[128], d2 = part[256], d3 = part[384];
    float m = fmaxf(fmaxf(d0, d1), fmaxf(d2, d3));
    float e0 = expf(d0 - m), e1 = expf(d1 - m), e2 = expf(d2 - m), e3 = expf(d3 - m);
    float inv = 1.f / (e0 + e1 + e2 + e3);
    if (tid < 500) {
        const float* s0 = sess + ((size_t)(b * J_ * 31 + s)) * H_ + tid;
        const size_t js = (size_t)31 * H_;
        float r = e0 * inv * s0[0] + e1 * inv * s0[js] + e2 * inv * s0[2 * js] + e3 * inv * s0[3 * js];
        att1[((size_t)(b * 31 + s)) * H_ + tid] = r;
    }
}

// ---------------- attention 2 ----------------
__global__ __launch_bounds__(512) void k_att2(const float* __restrict__ sess,
                                              const float* __restrict__ outy,
                                              const float* __restrict__ outm,
                                              const float* __restrict__ avgd,
                                              float* __restrict__ X) {
    int bi = blockIdx.x;   // B*31
    int s = bi % 31, b = bi / 31;
    __shared__ float vec[H_];
    __shared__ float part[512];
    int tid = threadIdx.x;
    if (tid < 500)
        vec[tid] = 0.5f * seluf(outy[((size_t)(b * 31 + s)) * H_ + tid]) +
                   0.5f * outm[((size_t)(b * S_ + s)) * H_ + tid];
    __syncthreads();
    int j = tid >> 7, i = tid & 127;
    const float* sp = sess + ((size_t)((b * J_ + j) * 31 + s)) * H_;
    float acc = 0.f;
    for (int h = i; h < H_; h += 128) acc += sp[h] * vec[h];
    part[tid] = acc;
    __syncthreads();
    for (int off = 64; off > 0; off >>= 1) {
        if (i < off) part[tid] += part[tid + off];
        __syncthreads();
    }
    float d0 = part[0]   / avgd[(b * J_ + 0) * 31 + s];
    float d1 = part[128] / avgd[(b * J_ + 1) * 31 + s];
    float d2 = part[256] / avgd[(b * J_ + 2) * 31 + s];
    float d3 = part[384] / avgd[(b * J_ + 3) * 31 + s];
    float m = fmaxf(fmaxf(d0, d1), fmaxf(d2, d3));
    float e0 = expf(d0 - m), e1 = expf(d1 - m), e2 = expf(d2 - m), e3 = expf(d3 - m);
    float inv = 1.f / (e0 + e1 + e2 + e3);
    if (tid < 500) {
        const float* s0 = sess + ((size_t)(b * J_ * 31 + s)) * H_ + tid;
        const size_t js = (size_t)31 * H_;
        float r = e0 * inv * s0[0] + e1 * inv * s0[js] + e2 * inv * s0[2 * js] + e3 * inv * s0[3 * js];
        X[((size_t)(b * S_ + s)) * 1000 + tid] = seluf(r);
    }
}

// ---------------- mix ----------------
__global__ __launch_bounds__(512) void k_mix(const float* __restrict__ outm,
                                             const float* __restrict__ outh,
                                             float* __restrict__ X) {
    int bs = blockIdx.x;   // B*S
    int tid = threadIdx.x;
    if (tid >= 500) return;
    size_t idx = (size_t)bs * H_ + tid;
    float om = 0.5f * (seluf(outm[idx]) + seluf(outh[idx]));
    X[(size_t)bs * 1000 + 500 + tid] = om;
    if ((bs & (S_ - 1)) == S_ - 1) X[(size_t)bs * 1000 + tid] = 0.f;
}

// ---------------- in-place log_softmax over rows of 5000 ----------------
__global__ __launch_bounds__(512) void k_lsm(float* __restrict__ out) {
    int row = blockIdx.x, tid = threadIdx.x;
    float* p = out + (size_t)row * NI_;
    __shared__ float red[512];
    float m = -1e30f;
    for (int i = tid; i < NI_; i += 512) m = fmaxf(m, p[i]);
    red[tid] = m;
    __syncthreads();
    for (int off = 256; off > 0; off >>= 1) {
        if (tid < off) red[tid] = fmaxf(red[tid], red[tid + off]);
        __syncthreads();
    }
    m = red[0];
    __syncthreads();
    float sm = 0.f;
    for (int i = tid; i < NI_; i += 512) sm += expf(p[i] - m);
    red[tid] = sm;
    __syncthreads();
    for (int off = 256; off > 0; off >>= 1) {
        if (tid < off) red[tid] += red[tid + off];
        __syncthreads();
    }
    float lse = m + logf(red[0]);
    __syncthreads();
    for (int i = tid; i < NI_; i += 512) p[i] -= lse;
}

extern "C" void kernel_launch(void* const* d_in, const int* in_sizes, int n_in,
                              void* d_out, int out_size, void* d_ws, size_t ws_size,
                              hipStream_t stream) {
    const int* item_vectors = (const int*)d_in[0];
    const int* sequence_tim = (const int*)d_in[1];
    const int* dilated_idx  = (const int*)d_in[2];
    const int* hist_items   = (const int*)d_in[3];
    const int* hist_tims    = (const int*)d_in[4];
    const float* mask       = (const float*)d_in[5];
    const float* tim_sim    = (const float*)d_in[6];
    const float* poi_dist   = (const float*)d_in[7];
    const float* emb_W      = (const float*)d_in[8];
    const float* lstm_Wi    = (const float*)d_in[9];
    const float* lstm_Wh    = (const float*)d_in[10];
    const float* lstm_b     = (const float*)d_in[11];
    const float* hist_Wi    = (const float*)d_in[12];
    const float* hist_Wh    = (const float*)d_in[13];
    const float* hist_b     = (const float*)d_in[14];
    const float* dil_Wi     = (const float*)d_in[15];
    const float* dil_Wh     = (const float*)d_in[16];
    const float* dil_b      = (const float*)d_in[17];
    const float* lin1_W     = (const float*)d_in[18];
    const float* lin1_b     = (const float*)d_in[19];
    const float* lin_W      = (const float*)d_in[20];
    const float* lin_b      = (const float*)d_in[21];
    float* out = (float*)d_out;
    float* ws  = (float*)d_ws;

    // workspace layout (float offsets)
    float* items   = ws + 0;        // 128000
    float* histemb = ws + 128000;   // 512000
    float* xwm     = ws + 640000;   // 512000
    float* xwd     = ws + 1152000;  // 512000
    float* xwh     = ws + 1664000;  // 2048000
    float* outm    = ws + 3712000;  // 128000
    float* outh    = ws + 3840000;  // 128000
    float* csg     = ws + 3968000;  // 128000
    float* he      = ws + 4096000;  // 512000
    float* pooled  = ws + 4608000;  // 4000
    float* sess    = ws + 4612000;  // 496000
    float* avgd    = ws + 5108000;  // 992
    float* att1    = ws + 5108992;  // 124000
    float* outy    = ws + 5232992;  // 124000
    float* Xbuf    = ws + 5356992;  // 256000
    int*   flags   = (int*)(ws + 5612992);  // 3*16*32 ints (padded)

    k_zero<<<dim3(6), dim3(256), 0, stream>>>(flags, 3 * NB_ * FPAD_);
    k_embed<<<dim3(1280), dim3(128), 0, stream>>>(item_vectors, hist_items, emb_W, items, histemb);

    // input-side GEMMs with bias folded in
    k_gemm_bt<<<dim3(32, 4), dim3(256), 0, stream>>>(items, lstm_Wi, lstm_b, xwm, 256, G4_, E_);
    k_gemm_bt<<<dim3(32, 4), dim3(256), 0, stream>>>(items, dil_Wi, dil_b, xwd, 256, G4_, E_);
    k_gemm_bt<<<dim3(32, 16), dim3(256), 0, stream>>>(histemb, hist_Wi, hist_b, xwh, 1024, G4_, E_);

    k_rec7<<<dim3(3 * NB_), dim3(TPB_), 0, stream>>>(
        xwm, lstm_Wh, xwd, dil_Wh, dilated_idx, xwh, hist_Wh,
        outm, outh, csg, he, flags);

    k_pool<<<dim3(B_), dim3(512), 0, stream>>>(outm, mask, pooled);
    k_sess<<<dim3(B_ * J_ * 31), dim3(512), 0, stream>>>(sequence_tim, item_vectors, hist_tims,
                                                         hist_items, tim_sim, poi_dist, he, sess, avgd);
    k_att1<<<dim3(B_ * 31), dim3(512), 0, stream>>>(sess, pooled, att1);
    k_gemm_bt<<<dim3(8, 4), dim3(256), 0, stream>>>(att1, lin1_W, lin1_b, outy, 248, H_, H_);
    k_att2<<<dim3(B_ * 31), dim3(512), 0, stream>>>(sess, outy, outm, avgd, Xbuf);
    k_mix<<<dim3(B_ * S_), dim3(512), 0, stream>>>(outm, outh, Xbuf);

    k_gemm_bt<<<dim3(79, 4), dim3(256), 0, stream>>>(Xbuf, lin_W, lin_b, out, 256, NI_, 1000);
    k_lsm<<<dim3(256), dim3(512), 0, stream>>>(out);
}

// Round 8
// 2427.373 us; speedup vs baseline: 1.1342x; 1.1342x over previous
//
#include <hip/hip_runtime.h>
#include <hip/hip_bf16.h>
#include <math.h>

// Problem constants
#define B_ 8
#define S_ 32
#define J_ 4
#define L_ 32
#define E_ 500
#define H_ 500
#define NI_ 5000
#define NT_ 48
#define G4_ 2000   // 4*H

#define NB_ 25     // blocks per recurrent gang
#define RPB_ 20    // h indices per block (25*20 = 500)
#define TPB_ 704   // 640 compute threads + 64 stager threads (wave 10)

typedef unsigned long long ull;

__device__ __forceinline__ float sigm(float x) { return 1.f / (1.f + expf(-x)); }
__device__ __forceinline__ float seluf(float x) {
    const float sc = 1.0507009873554805f, al = 1.6732632423543772f;
    return x > 0.f ? sc * x : sc * al * (expf(x) - 1.f);
}
// agent-scope ops: bypass L1/L2, coherent at L3; no fences / no wbl2
__device__ __forceinline__ float cohload(const float* p) {
    return __hip_atomic_load(p, __ATOMIC_RELAXED, __HIP_MEMORY_SCOPE_AGENT);
}
__device__ __forceinline__ ull cohload64(const ull* p) {
    return __hip_atomic_load(p, __ATOMIC_RELAXED, __HIP_MEMORY_SCOPE_AGENT);
}
__device__ __forceinline__ void cohstore(float* p, float v) {
    __hip_atomic_store(p, v, __ATOMIC_RELAXED, __HIP_MEMORY_SCOPE_AGENT);
}

// ---------------- zero the flag slots ----------------
__global__ void k_zero(int* p, int n) {
    int i = blockIdx.x * blockDim.x + threadIdx.x;
    if (i < n) __hip_atomic_store(&p[i], 0, __ATOMIC_RELAXED, __HIP_MEMORY_SCOPE_AGENT);
}

// ---------------- embedding gather ----------------
__global__ __launch_bounds__(128) void k_embed(const int* __restrict__ itemv,
                                               const int* __restrict__ histi,
                                               const float* __restrict__ embW,
                                               float* __restrict__ items,
                                               float* __restrict__ histemb) {
    int row = blockIdx.x;
    int id;
    float* dst;
    if (row < 256) { id = itemv[row]; dst = items + (size_t)row * E_; }
    else           { int rr = row - 256; id = histi[rr]; dst = histemb + (size_t)rr * E_; }
    const float4* s = (const float4*)(embW + (size_t)id * E_);
    float4* d = (float4*)dst;
    if (threadIdx.x < 125) d[threadIdx.x] = s[threadIdx.x];
}

// ---------------- generic GEMM: C[M,N] = A[M,K] @ B[N,K]^T + bias[N] ----------------
#define TBM 64
#define TBN 64
#define TBK 16
__global__ __launch_bounds__(256) void k_gemm_bt(const float* __restrict__ A,
                                                 const float* __restrict__ Bm,
                                                 const float* __restrict__ bias,
                                                 float* __restrict__ C,
                                                 int M, int N, int K) {
    __shared__ float As[TBK][TBM + 1];
    __shared__ float Bs[TBK][TBN + 1];
    const int tid = threadIdx.x;
    const int tx = tid & 15, ty = tid >> 4;
    const int row0 = blockIdx.y * TBM, col0 = blockIdx.x * TBN;
    float acc[4][4] = {};
    for (int k0 = 0; k0 < K; k0 += TBK) {
#pragma unroll
        for (int i = 0; i < 4; ++i) {
            int e = tid + i * 256;
            int kk = e & 15, m = e >> 4;
            int gk = k0 + kk;
            float va = 0.f, vb = 0.f;
            int gm = row0 + m, gn = col0 + m;
            if (gk < K) {
                if (gm < M) va = A[(size_t)gm * K + gk];
                if (gn < N) vb = Bm[(size_t)gn * K + gk];
            }
            As[kk][m] = va;
            Bs[kk][m] = vb;
        }
        __syncthreads();
#pragma unroll
        for (int kk = 0; kk < TBK; ++kk) {
            float a[4], bb[4];
#pragma unroll
            for (int i = 0; i < 4; ++i) a[i] = As[kk][ty * 4 + i];
#pragma unroll
            for (int i = 0; i < 4; ++i) bb[i] = Bs[kk][tx * 4 + i];
#pragma unroll
            for (int i = 0; i < 4; ++i)
#pragma unroll
                for (int j = 0; j < 4; ++j) acc[i][j] += a[i] * bb[j];
        }
        __syncthreads();
    }
#pragma unroll
    for (int i = 0; i < 4; ++i) {
        int gm = row0 + ty * 4 + i;
        if (gm >= M) continue;
#pragma unroll
        for (int j = 0; j < 4; ++j) {
            int gn = col0 + tx * 4 + j;
            if (gn < N) C[(size_t)gm * N + gn] = acc[i][j] + (bias ? bias[gn] : 0.f);
        }
    }
}

// ---------------- multi-block batched recurrent kernel (v8) ----------------
// v5 skeleton + pipelined chunk handoff:
//   wave 10 (tid 640..703) = stager: polls the 25 producer flags; per arrived
//   producer p, copies its 20-k chunk (8 batches x 20 floats) from global
//   (uncached) into h_s and release-stores ready[p]=t (LDS, workgroup scope).
//   Compute waves spin on ready[p] (LDS broadcast read) then FMA that chunk.
//   Own-block chunk (roles 0/2) short-circuits through LDS: gate threads write
//   h into h_s directly; tid0 bumps ready[blk] after the barrier.
__global__ __launch_bounds__(TPB_) void k_rec8(
    const float* __restrict__ xwm, const float* __restrict__ Whm,
    const float* __restrict__ xwd, const float* __restrict__ Whd,
    const int* __restrict__ dilidx,
    const float* __restrict__ xwh, const float* __restrict__ Whh,
    float* __restrict__ outm, float* __restrict__ outh,
    float* __restrict__ csg, float* __restrict__ he,
    int* __restrict__ flags) {
    __shared__ __align__(16) float h_s[8][500];
    __shared__ float z_s[80][8];
    __shared__ float c_s[RPB_][8];
    __shared__ int ready[NB_];
    const int tid = threadIdx.x;
    const int gb = blockIdx.x;
    const int role = gb / NB_;          // 0 main, 1 dil, 2 hist
    const int blk = gb - role * NB_;
    const int r0 = blk * RPB_;

    const float* Wh   = (role == 0) ? Whm : (role == 1) ? Whd : Whh;
    const float* xw   = (role == 0) ? xwm : (role == 1) ? xwd : xwh;
    const float* exch = (role == 0) ? outm : (role == 1) ? outh : he;
    const int nsteps  = (role == 2) ? 128 : 32;
    const int rstride = (role == 2) ? 128 : S_;
    int* flag = flags + role * 32;      // NB_ slots used
    const bool own_lds = (role != 1);   // own-chunk LDS short-circuit valid?

    const bool is_stager = (tid >= 640);
    const int lane = tid - 640;         // stager lane 0..63

    // compute-thread geometry (v5 layout: c = col-in-block, b = batch)
    const int c = is_stager ? 0 : (tid >> 3);   // 0..79
    const int b = tid & 7;
    const int gate = c / RPB_;
    const int ri = c - gate * RPB_;
    const int col = gate * 500 + r0 + ri;
    const float4* wp4 = (const float4*)(Wh + (size_t)col * 500);

    if (tid < RPB_ * 8) c_s[tid >> 3][tid & 7] = 0.f;
    if (tid < NB_) ready[tid] = 0;
    __syncthreads();

    for (int t = 0; t < nsteps; ++t) {
        float acc = 0.f;
        float pc_r = 0.f;
        if (!is_stager)
            acc = xw[((size_t)(b * nsteps + t)) * G4_ + col];   // xw prefetch

        if (t > 0) {
            if (is_stager) {
                // ---- stager: poll flags, stage chunks as they arrive ----
                unsigned done = own_lds ? (1u << blk) : 0u;
                const unsigned ALL = (1u << NB_) - 1u;
                while (done != ALL) {
                    int v = 0;
                    if (lane < NB_ && !((done >> lane) & 1u))
                        v = __hip_atomic_load(&flag[lane], __ATOMIC_RELAXED,
                                              __HIP_MEMORY_SCOPE_AGENT);
                    ull rdy = __ballot(lane < NB_ && v >= t);
                    if (!rdy) { __builtin_amdgcn_s_sleep(1); continue; }
                    while (rdy) {
                        int p = (int)(__ffsll(rdy) - 1); rdy &= rdy - 1;
                        if (lane < 40) {   // 8 batches x 5 float4 segs
                            int bS = lane / 5, seg = lane - bS * 5;
                            int row = (role == 1) ? dilidx[bS * S_ + t] : (t - 1);
                            const ull* src = (const ull*)(exch +
                                ((size_t)(bS * rstride + row)) * H_ + p * RPB_ + seg * 4);
                            ull u0 = cohload64(src);
                            ull u1 = cohload64(src + 1);
                            union { ull u[2]; float4 f; } uf;
                            uf.u[0] = u0; uf.u[1] = u1;
                            *(float4*)&h_s[bS][p * RPB_ + seg * 4] = uf.f;
                        }
                        if (lane == 0)
                            __hip_atomic_store(&ready[p], t, __ATOMIC_RELEASE,
                                               __HIP_MEMORY_SCOPE_WORKGROUP);
                        done |= 1u << p;
                    }
                }
            } else {
                // ---- compute: per-chunk spin + FMA (k = [20p, 20p+20)) ----
                const float4* hp4 = (const float4*)&h_s[b][0];
                float s0 = 0.f, s1 = 0.f, s2 = 0.f, s3 = 0.f;
                for (int p = 0; p < NB_; ++p) {
                    while (__hip_atomic_load(&ready[p], __ATOMIC_ACQUIRE,
                                             __HIP_MEMORY_SCOPE_WORKGROUP) < t) {}
                    int k4 = p * 5;
                    float4 h0 = hp4[k4],     w0 = wp4[k4];
                    float4 h1 = hp4[k4 + 1], w1 = wp4[k4 + 1];
                    float4 h2 = hp4[k4 + 2], w2 = wp4[k4 + 2];
                    float4 h3 = hp4[k4 + 3], w3 = wp4[k4 + 3];
                    float4 h4 = hp4[k4 + 4], w4 = wp4[k4 + 4];
                    s0 += w0.x * h0.x + w0.y * h0.y + w0.z * h0.z + w0.w * h0.w;
                    s1 += w1.x * h1.x + w1.y * h1.y + w1.z * h1.z + w1.w * h1.w;
                    s2 += w2.x * h2.x + w2.y * h2.y + w2.z * h2.z + w2.w * h2.w;
                    s3 += w3.x * h3.x + w3.y * h3.y + w3.z * h3.z + w3.w * h3.w;
                    s0 += w4.x * h4.x + w4.y * h4.y + w4.z * h4.z + w4.w * h4.w;
                }
                acc += (s0 + s1) + (s2 + s3);
                // role-1 prev-cell gather (own indices, written by this block)
                if (role == 1 && tid < RPB_ * 8) {
                    int it = dilidx[b * S_ + t];
                    pc_r = cohload(&csg[((size_t)(b * S_ + it)) * H_ + r0 + (tid >> 3)]);
                }
            }
        }
        if (!is_stager) z_s[c][b] = acc;
        __syncthreads();   // A

        // ---- gate update for this block's 20 h-indices ----
        if (tid < RPB_ * 8) {
            int rr = tid >> 3, bb = tid & 7;
            float zi = z_s[rr][bb];
            float zf = z_s[RPB_ + rr][bb];
            float zg = z_s[2 * RPB_ + rr][bb];
            float zo = z_s[3 * RPB_ + rr][bb];
            int r = r0 + rr;
            float pc = (role == 1) ? pc_r : c_s[rr][bb];
            float cc = sigm(zf) * pc + sigm(zi) * tanhf(zg);
            float hh = sigm(zo) * tanhf(cc);
            if (role == 0) {
                c_s[rr][bb] = cc;
                cohstore(&outm[((size_t)(bb * S_ + t)) * H_ + r], hh);
                h_s[bb][r] = hh;                       // own-chunk short-circuit
            } else if (role == 2) {
                c_s[rr][bb] = cc;
                cohstore(&he[((size_t)(bb * 128 + t)) * H_ + r], hh);
                h_s[bb][r] = hh;                       // own-chunk short-circuit
            } else {
                cohstore(&outh[((size_t)(bb * S_ + t)) * H_ + r], hh);
                cohstore(&csg[((size_t)(bb * S_ + t)) * H_ + r], cc);
            }
        }
        __syncthreads();   // B: drains vmcnt(0) (stores at L3) + orders h_s writes
        if (tid == 0) {
            __hip_atomic_store(&flag[blk], t + 1, __ATOMIC_RELAXED,
                               __HIP_MEMORY_SCOPE_AGENT);
            if (own_lds)
                __hip_atomic_store(&ready[blk], t + 1, __ATOMIC_RELAXED,
                                   __HIP_MEMORY_SCOPE_WORKGROUP);
        }
    }
}

// ---------------- masked mean pooling ----------------
__global__ __launch_bounds__(512) void k_pool(const float* __restrict__ outm,
                                              const float* __restrict__ mask,
                                              float* __restrict__ pooled) {
    int b = blockIdx.x, tid = threadIdx.x;
    if (tid >= 500) return;
    float acc = 0.f, den = 0.f;
    for (int s = 0; s < S_; ++s) {
        float mk = mask[b * S_ + s];
        acc += outm[((size_t)(b * S_ + s)) * H_ + tid] * mk;
        den += mk;
    }
    pooled[b * H_ + tid] = acc / den;
}

// ---------------- session rep: sess[b,j,s,:] and avgd[b,j,s] ----------------
__global__ __launch_bounds__(512) void k_sess(const int* __restrict__ seqtim,
                                              const int* __restrict__ itemv,
                                              const int* __restrict__ histt,
                                              const int* __restrict__ histi,
                                              const float* __restrict__ timsim,
                                              const float* __restrict__ poid,
                                              const float* __restrict__ he,
                                              float* __restrict__ sess,
                                              float* __restrict__ avgd) {
    int bi = blockIdx.x;                // B*J*31
    int s = bi % 31;
    int tmpv = bi / 31;
    int j = tmpv & 3, b = tmpv >> 2;
    __shared__ float w[L_];
    __shared__ float pd[L_];
    __shared__ float stats[1];
    int tid = threadIdx.x;
    int st = seqtim[b * S_ + s];
    if (tid < L_) {
        int ht = histt[(b * J_ + j) * L_ + tid];
        w[tid] = timsim[st * NT_ + ht];
    }
    if (tid >= 64 && tid < 64 + L_) {   // parallel poi_dist gather
        int l = tid - 64;
        int iv = itemv[b * S_ + s];
        pd[l] = poid[(size_t)iv * NI_ + histi[(b * J_ + j) * L_ + l]];
    }
    __syncthreads();
    if (tid == 64) {
        float a = 0.f;
        for (int l = 0; l < L_; ++l) a += pd[l];
        avgd[(b * J_ + j) * 31 + s] = a * (1.f / 32.f);
    }
    if (tid == 0) {
        float m = -1e30f;
        for (int l = 0; l < L_; ++l) m = fmaxf(m, w[l]);
        float sm = 0.f;
        for (int l = 0; l < L_; ++l) { float e = expf(w[l] - m); w[l] = e; sm += e; }
        stats[0] = 1.f / sm;
    }
    __syncthreads();
    if (tid < 500) {
        float inv = stats[0];
        float acc = 0.f;
        const float* hp = he + ((size_t)(b * J_ * L_ + j * L_)) * H_ + tid;
        for (int l = 0; l < L_; ++l) acc += w[l] * inv * hp[(size_t)l * H_];
        sess[((size_t)((b * J_ + j) * 31 + s)) * H_ + tid] = acc;
    }
}

// ---------------- attention 1 ----------------
__global__ __launch_bounds__(512) void k_att1(const float* __restrict__ sess,
                                              const float* __restrict__ pooled,
                                              float* __restrict__ att1) {
    int bi = blockIdx.x;   // B*31
    int s = bi % 31, b = bi / 31;
    __shared__ float vec[H_];
    __shared__ float part[512];
    int tid = threadIdx.x;
    if (tid < 500) vec[tid] = pooled[b * H_ + tid];
    __syncthreads();
    int j = tid >> 7, i = tid & 127;
    const float* sp = sess + ((size_t)((b * J_ + j) * 31 + s)) * H_;
    float acc = 0.f;
    for (int h = i; h < H_; h += 128) acc += sp[h] * vec[h];
    part[tid] = acc;
    __syncthreads();
    for (int off = 64; off > 0; off >>= 1) {
        if (i < off) part[tid] += part[tid + off];
        __syncthreads();
    }
    float d0 = part[0], d1 = part[128], d2 = part[256], d3 = part[384];
    float m = fmaxf(fmaxf(d0, d1), fmaxf(d2, d3));
    float e0 = expf(d0 - m), e1 = expf(d1 - m), e2 = expf(d2 - m), e3 = expf(d3 - m);
    float inv = 1.f / (e0 + e1 + e2 + e3);
    if (tid < 500) {
        const float* s0 = sess + ((size_t)(b * J_ * 31 + s)) * H_ + tid;
        const size_t js = (size_t)31 * H_;
        float r = e0 * inv * s0[0] + e1 * inv * s0[js] + e2 * inv * s0[2 * js] + e3 * inv * s0[3 * js];
        att1[((size_t)(b * 31 + s)) * H_ + tid] = r;
    }
}

// ---------------- attention 2 ----------------
__global__ __launch_bounds__(512) void k_att2(const float* __restrict__ sess,
                                              const float* __restrict__ outy,
                                              const float* __restrict__ outm,
                                              const float* __restrict__ avgd,
                                              float* __restrict__ X) {
    int bi = blockIdx.x;   // B*31
    int s = bi % 31, b = bi / 31;
    __shared__ float vec[H_];
    __shared__ float part[512];
    int tid = threadIdx.x;
    if (tid < 500)
        vec[tid] = 0.5f * seluf(outy[((size_t)(b * 31 + s)) * H_ + tid]) +
                   0.5f * outm[((size_t)(b * S_ + s)) * H_ + tid];
    __syncthreads();
    int j = tid >> 7, i = tid & 127;
    const float* sp = sess + ((size_t)((b * J_ + j) * 31 + s)) * H_;
    float acc = 0.f;
    for (int h = i; h < H_; h += 128) acc += sp[h] * vec[h];
    part[tid] = acc;
    __syncthreads();
    for (int off = 64; off > 0; off >>= 1) {
        if (i < off) part[tid] += part[tid + off];
        __syncthreads();
    }
    float d0 = part[0]   / avgd[(b * J_ + 0) * 31 + s];
    float d1 = part[128] / avgd[(b * J_ + 1) * 31 + s];
    float d2 = part[256] / avgd[(b * J_ + 2) * 31 + s];
    float d3 = part[384] / avgd[(b * J_ + 3) * 31 + s];
    float m = fmaxf(fmaxf(d0, d1), fmaxf(d2, d3));
    float e0 = expf(d0 - m), e1 = expf(d1 - m), e2 = expf(d2 - m), e3 = expf(d3 - m);
    float inv = 1.f / (e0 + e1 + e2 + e3);
    if (tid < 500) {
        const float* s0 = sess + ((size_t)(b * J_ * 31 + s)) * H_ + tid;
        const size_t js = (size_t)31 * H_;
        float r = e0 * inv * s0[0] + e1 * inv * s0[js] + e2 * inv * s0[2 * js] + e3 * inv * s0[3 * js];
        X[((size_t)(b * S_ + s)) * 1000 + tid] = seluf(r);
    }
}

// ---------------- mix ----------------
__global__ __launch_bounds__(512) void k_mix(const float* __restrict__ outm,
                                             const float* __restrict__ outh,
                                             float* __restrict__ X) {
    int bs = blockIdx.x;   // B*S
    int tid = threadIdx.x;
    if (tid >= 500) return;
    size_t idx = (size_t)bs * H_ + tid;
    float om = 0.5f * (seluf(outm[idx]) + seluf(outh[idx]));
    X[(size_t)bs * 1000 + 500 + tid] = om;
    if ((bs & (S_ - 1)) == S_ - 1) X[(size_t)bs * 1000 + tid] = 0.f;
}

// ---------------- in-place log_softmax over rows of 5000 ----------------
__global__ __launch_bounds__(512) void k_lsm(float* __restrict__ out) {
    int row = blockIdx.x, tid = threadIdx.x;
    float* p = out + (size_t)row * NI_;
    __shared__ float red[512];
    float m = -1e30f;
    for (int i = tid; i < NI_; i += 512) m = fmaxf(m, p[i]);
    red[tid] = m;
    __syncthreads();
    for (int off = 256; off > 0; off >>= 1) {
        if (tid < off) red[tid] = fmaxf(red[tid], red[tid + off]);
        __syncthreads();
    }
    m = red[0];
    __syncthreads();
    float sm = 0.f;
    for (int i = tid; i < NI_; i += 512) sm += expf(p[i] - m);
    red[tid] = sm;
    __syncthreads();
    for (int off = 256; off > 0; off >>= 1) {
        if (tid < off) red[tid] += red[tid + off];
        __syncthreads();
    }
    float lse = m + logf(red[0]);
    __syncthreads();
    for (int i = tid; i < NI_; i += 512) p[i] -= lse;
}

extern "C" void kernel_launch(void* const* d_in, const int* in_sizes, int n_in,
                              void* d_out, int out_size, void* d_ws, size_t ws_size,
                              hipStream_t stream) {
    const int* item_vectors = (const int*)d_in[0];
    const int* sequence_tim = (const int*)d_in[1];
    const int* dilated_idx  = (const int*)d_in[2];
    const int* hist_items   = (const int*)d_in[3];
    const int* hist_tims    = (const int*)d_in[4];
    const float* mask       = (const float*)d_in[5];
    const float* tim_sim    = (const float*)d_in[6];
    const float* poi_dist   = (const float*)d_in[7];
    const float* emb_W      = (const float*)d_in[8];
    const float* lstm_Wi    = (const float*)d_in[9];
    const float* lstm_Wh    = (const float*)d_in[10];
    const float* lstm_b     = (const float*)d_in[11];
    const float* hist_Wi    = (const float*)d_in[12];
    const float* hist_Wh    = (const float*)d_in[13];
    const float* hist_b     = (const float*)d_in[14];
    const float* dil_Wi     = (const float*)d_in[15];
    const float* dil_Wh     = (const float*)d_in[16];
    const float* dil_b      = (const float*)d_in[17];
    const float* lin1_W     = (const float*)d_in[18];
    const float* lin1_b     = (const float*)d_in[19];
    const float* lin_W      = (const float*)d_in[20];
    const float* lin_b      = (const float*)d_in[21];
    float* out = (float*)d_out;
    float* ws  = (float*)d_ws;

    // workspace layout (float offsets)
    float* items   = ws + 0;        // 128000
    float* histemb = ws + 128000;   // 512000
    float* xwm     = ws + 640000;   // 512000
    float* xwd     = ws + 1152000;  // 512000
    float* xwh     = ws + 1664000;  // 2048000
    float* outm    = ws + 3712000;  // 128000
    float* outh    = ws + 3840000;  // 128000
    float* csg     = ws + 3968000;  // 128000
    float* he      = ws + 4096000;  // 512000
    float* pooled  = ws + 4608000;  // 4000
    float* sess    = ws + 4612000;  // 496000
    float* avgd    = ws + 5108000;  // 992
    float* att1    = ws + 5108992;  // 124000
    float* outy    = ws + 5232992;  // 124000
    float* Xbuf    = ws + 5356992;  // 256000
    int*   flags   = (int*)(ws + 5612992);  // 3*32 ints

    k_zero<<<dim3(1), dim3(128), 0, stream>>>(flags, 96);
    k_embed<<<dim3(1280), dim3(128), 0, stream>>>(item_vectors, hist_items, emb_W, items, histemb);

    // input-side GEMMs with bias folded in
    k_gemm_bt<<<dim3(32, 4), dim3(256), 0, stream>>>(items, lstm_Wi, lstm_b, xwm, 256, G4_, E_);
    k_gemm_bt<<<dim3(32, 4), dim3(256), 0, stream>>>(items, dil_Wi, dil_b, xwd, 256, G4_, E_);
    k_gemm_bt<<<dim3(32, 16), dim3(256), 0, stream>>>(histemb, hist_Wi, hist_b, xwh, 1024, G4_, E_);

    k_rec8<<<dim3(3 * NB_), dim3(TPB_), 0, stream>>>(
        xwm, lstm_Wh, xwd, dil_Wh, dilated_idx, xwh, hist_Wh,
        outm, outh, csg, he, flags);

    k_pool<<<dim3(B_), dim3(512), 0, stream>>>(outm, mask, pooled);
    k_sess<<<dim3(B_ * J_ * 31), dim3(512), 0, stream>>>(sequence_tim, item_vectors, hist_tims,
                                                         hist_items, tim_sim, poi_dist, he, sess, avgd);
    k_att1<<<dim3(B_ * 31), dim3(512), 0, stream>>>(sess, pooled, att1);
    k_gemm_bt<<<dim3(8, 4), dim3(256), 0, stream>>>(att1, lin1_W, lin1_b, outy, 248, H_, H_);
    k_att2<<<dim3(B_ * 31), dim3(512), 0, stream>>>(sess, outy, outm, avgd, Xbuf);
    k_mix<<<dim3(B_ * S_), dim3(512), 0, stream>>>(outm, outh, Xbuf);

    k_gemm_bt<<<dim3(79, 4), dim3(256), 0, stream>>>(Xbuf, lin_W, lin_b, out, 256, NI_, 1000);
    k_lsm<<<dim3(256), dim3(512), 0, stream>>>(out);
}

// Round 9
// 1834.842 us; speedup vs baseline: 1.5005x; 1.3229x over previous
//
#include <hip/hip_runtime.h>
#include <hip/hip_bf16.h>
#include <math.h>

// Problem constants
#define B_ 8
#define S_ 32
#define J_ 4
#define L_ 32
#define E_ 500
#define H_ 500
#define NI_ 5000
#define NT_ 48
#define G4_ 2000   // 4*H

#define FPAD_ 32   // flag slot padding (128 B)

typedef unsigned long long ull;

__device__ __forceinline__ float sigm(float x) { return 1.f / (1.f + expf(-x)); }
__device__ __forceinline__ float seluf(float x) {
    const float sc = 1.0507009873554805f, al = 1.6732632423543772f;
    return x > 0.f ? sc * x : sc * al * (expf(x) - 1.f);
}
// agent-scope ops: bypass L1/L2, coherent at L3; no fences / no wbl2
__device__ __forceinline__ float cohload(const float* p) {
    return __hip_atomic_load(p, __ATOMIC_RELAXED, __HIP_MEMORY_SCOPE_AGENT);
}
__device__ __forceinline__ ull cohload64(const ull* p) {
    return __hip_atomic_load(p, __ATOMIC_RELAXED, __HIP_MEMORY_SCOPE_AGENT);
}
__device__ __forceinline__ void cohstore(float* p, float v) {
    __hip_atomic_store(p, v, __ATOMIC_RELAXED, __HIP_MEMORY_SCOPE_AGENT);
}

// ---------------- zero the flag slots ----------------
__global__ void k_zero(int* p, int n) {
    int i = blockIdx.x * blockDim.x + threadIdx.x;
    if (i < n) __hip_atomic_store(&p[i], 0, __ATOMIC_RELAXED, __HIP_MEMORY_SCOPE_AGENT);
}

// ---------------- embedding gather ----------------
__global__ __launch_bounds__(128) void k_embed(const int* __restrict__ itemv,
                                               const int* __restrict__ histi,
                                               const float* __restrict__ embW,
                                               float* __restrict__ items,
                                               float* __restrict__ histemb) {
    int row = blockIdx.x;
    int id;
    float* dst;
    if (row < 256) { id = itemv[row]; dst = items + (size_t)row * E_; }
    else           { int rr = row - 256; id = histi[rr]; dst = histemb + (size_t)rr * E_; }
    const float4* s = (const float4*)(embW + (size_t)id * E_);
    float4* d = (float4*)dst;
    if (threadIdx.x < 125) d[threadIdx.x] = s[threadIdx.x];
}

// ---------------- generic GEMM: C[M,N] = A[M,K] @ B[N,K]^T + bias[N] ----------------
#define TBM 64
#define TBN 64
#define TBK 16
__global__ __launch_bounds__(256) void k_gemm_bt(const float* __restrict__ A,
                                                 const float* __restrict__ Bm,
                                                 const float* __restrict__ bias,
                                                 float* __restrict__ C,
                                                 int M, int N, int K) {
    __shared__ float As[TBK][TBM + 1];
    __shared__ float Bs[TBK][TBN + 1];
    const int tid = threadIdx.x;
    const int tx = tid & 15, ty = tid >> 4;
    const int row0 = blockIdx.y * TBM, col0 = blockIdx.x * TBN;
    float acc[4][4] = {};
    for (int k0 = 0; k0 < K; k0 += TBK) {
#pragma unroll
        for (int i = 0; i < 4; ++i) {
            int e = tid + i * 256;
            int kk = e & 15, m = e >> 4;
            int gk = k0 + kk;
            float va = 0.f, vb = 0.f;
            int gm = row0 + m, gn = col0 + m;
            if (gk < K) {
                if (gm < M) va = A[(size_t)gm * K + gk];
                if (gn < N) vb = Bm[(size_t)gn * K + gk];
            }
            As[kk][m] = va;
            Bs[kk][m] = vb;
        }
        __syncthreads();
#pragma unroll
        for (int kk = 0; kk < TBK; ++kk) {
            float a[4], bb[4];
#pragma unroll
            for (int i = 0; i < 4; ++i) a[i] = As[kk][ty * 4 + i];
#pragma unroll
            for (int i = 0; i < 4; ++i) bb[i] = Bs[kk][tx * 4 + i];
#pragma unroll
            for (int i = 0; i < 4; ++i)
#pragma unroll
                for (int j = 0; j < 4; ++j) acc[i][j] += a[i] * bb[j];
        }
        __syncthreads();
    }
#pragma unroll
    for (int i = 0; i < 4; ++i) {
        int gm = row0 + ty * 4 + i;
        if (gm >= M) continue;
#pragma unroll
        for (int j = 0; j < 4; ++j) {
            int gn = col0 + tx * 4 + j;
            if (gn < N) C[(size_t)gm * N + gn] = acc[i][j] + (bias ? bias[gn] : 0.f);
        }
    }
}

// ---------------- per-batch gang recurrent kernel (v9) ----------------
// 24 independent gangs, one per (role, batch):
//   role 0 (main): 8 gangs x 8 blocks, 63 h-idx/block, 32 steps, XCD 4-5
//   role 1 (dil):  8 gangs x 8 blocks, 63 h-idx/block, 32 steps, XCD 6-7
//   role 2 (hist): 8 gangs x 16 blocks, 32 h-idx/block, 128 steps, XCD 0-3
// Exchange payload per gang = ONE h row (500 floats = 2 KB). h is staged by
// 125 threads (one pipelined L3 round trip) and read broadcast from LDS
// (all lanes same address -> zero bank conflicts). Wh streams from the
// XCD-local L2 (each role's 4 MB W pinned to its XCD slice via blockIdx%8).
// Sync: padded per-block flag slots, relaxed agent ops only (protocol
// validated in v3/v5: barrier drains vmcnt -> stores at L3 before flag).
__global__ __launch_bounds__(256) void k_rec9(
    const float* __restrict__ xwm, const float* __restrict__ Whm,
    const float* __restrict__ xwd, const float* __restrict__ Whd,
    const int* __restrict__ dilidx,
    const float* __restrict__ xwh, const float* __restrict__ Whh,
    float* __restrict__ outm, float* __restrict__ outh,
    float* __restrict__ csg, float* __restrict__ he,
    int* __restrict__ flags) {
    __shared__ __align__(16) float4 h_s4[125];
    __shared__ float z_s[256];
    const int tid = threadIdx.x;
    const int bid = blockIdx.x;
    const int x = bid & 7, ii = bid >> 3;   // x ~ XCD slot (perf heuristic only)
    int role, b, blk, K;
    if (x < 4)      { role = 2; b = x * 2 + (ii >> 4);       blk = ii & 15; K = 16; }
    else if (x < 6) { role = 0; b = (x - 4) * 4 + (ii >> 3); blk = ii & 7;  K = 8; }
    else            { role = 1; b = (x - 6) * 4 + (ii >> 3); blk = ii & 7;  K = 8; }

    const int hpbb   = (role == 2) ? 32 : 63;
    const int r0     = blk * hpbb;
    const int hpb    = min(hpbb, 500 - r0);
    const int C      = 4 * hpb;
    const int nsteps = (role == 2) ? 128 : 32;

    const float* Wh = (role == 0) ? Whm : (role == 1) ? Whd : Whh;
    const float* xw = (role == 0) ? xwm : (role == 1) ? xwd : xwh;
    int* flag = flags + (role * 8 + b) * 16 * FPAD_;

    int colg = 0;
    if (tid < C) {
        int gate = tid / hpb;
        int ri = tid - gate * hpb;
        colg = gate * 500 + r0 + ri;
    }
    const float4* wp4 = (const float4*)(Wh + (size_t)colg * 500);

    float c_reg = 0.f;

    for (int t = 0; t < nsteps; ++t) {
        // xw prefetch (independent of h) -> issue before the poll
        float acc = 0.f;
        if (tid < C) acc = xw[((size_t)(b * nsteps + t)) * G4_ + colg];

        float pc_r = 0.f;
        if (t > 0) {
            // ---- wait for all K blocks of this gang to finish step t-1 ----
            if (tid < 64) {
                while (true) {
                    int v = (tid < K)
                        ? __hip_atomic_load(&flag[tid * FPAD_], __ATOMIC_RELAXED,
                                            __HIP_MEMORY_SCOPE_AGENT)
                        : 0x7fffffff;
                    if (__all(v >= t)) break;
                    __builtin_amdgcn_s_sleep(1);
                }
            }
            __syncthreads();

            // ---- stage this batch's h row (500 floats, one pipelined RT) ----
            const float* hrow;
            if (role == 0)      hrow = outm + ((size_t)(b * S_ + (t - 1))) * H_;
            else if (role == 2) hrow = he + ((size_t)(b * 128 + (t - 1))) * H_;
            else { int it = dilidx[b * S_ + t];
                   hrow = outh + ((size_t)(b * S_ + it)) * H_; }
            if (tid < 125) {
                const ull* p = (const ull*)(hrow + tid * 4);
                ull u0 = cohload64(p);
                ull u1 = cohload64(p + 1);
                union { ull u[2]; float4 f; } uf;
                uf.u[0] = u0; uf.u[1] = u1;
                h_s4[tid] = uf.f;
            }
            // role-1 prev-cell gather (own h-range, written by this block)
            if (role == 1 && tid < hpb) {
                int it = dilidx[b * S_ + t];
                pc_r = cohload(&csg[((size_t)(b * S_ + it)) * H_ + r0 + tid]);
            }
            __syncthreads();

            // ---- GEMV: dot(h, W[colg]); h reads are LDS broadcasts ----
            if (tid < C) {
                float s0 = 0.f, s1 = 0.f, s2 = 0.f, s3 = 0.f;
#pragma unroll 2
                for (int k4 = 0; k4 < 124; k4 += 4) {
                    float4 w0 = wp4[k4],     h0 = h_s4[k4];
                    float4 w1 = wp4[k4 + 1], h1 = h_s4[k4 + 1];
                    float4 w2 = wp4[k4 + 2], h2 = h_s4[k4 + 2];
                    float4 w3 = wp4[k4 + 3], h3 = h_s4[k4 + 3];
                    s0 += w0.x * h0.x + w0.y * h0.y + w0.z * h0.z + w0.w * h0.w;
                    s1 += w1.x * h1.x + w1.y * h1.y + w1.z * h1.z + w1.w * h1.w;
                    s2 += w2.x * h2.x + w2.y * h2.y + w2.z * h2.z + w2.w * h2.w;
                    s3 += w3.x * h3.x + w3.y * h3.y + w3.z * h3.z + w3.w * h3.w;
                }
                float4 wt = wp4[124], ht = h_s4[124];
                s0 += wt.x * ht.x + wt.y * ht.y + wt.z * ht.z + wt.w * ht.w;
                acc += (s0 + s1) + (s2 + s3);
            }
        }
        z_s[tid] = acc;
        __syncthreads();

        // ---- gate update for this block's hpb h-indices ----
        if (tid < hpb) {
            float zi = z_s[tid];
            float zf = z_s[tid + hpb];
            float zg = z_s[tid + 2 * hpb];
            float zo = z_s[tid + 3 * hpb];
            float pc = (role == 1) ? pc_r : c_reg;
            float cc = sigm(zf) * pc + sigm(zi) * tanhf(zg);
            float hh = sigm(zo) * tanhf(cc);
            c_reg = cc;
            int r = r0 + tid;
            if (role == 0) {
                cohstore(&outm[((size_t)(b * S_ + t)) * H_ + r], hh);
            } else if (role == 2) {
                cohstore(&he[((size_t)(b * 128 + t)) * H_ + r], hh);
            } else {
                cohstore(&outh[((size_t)(b * S_ + t)) * H_ + r], hh);
                cohstore(&csg[((size_t)(b * S_ + t)) * H_ + r], cc);
            }
        }
        __syncthreads();   // drains vmcnt(0): agent-scope stores complete at L3
        if (tid == 0)
            __hip_atomic_store(&flag[blk * FPAD_], t + 1, __ATOMIC_RELAXED,
                               __HIP_MEMORY_SCOPE_AGENT);
    }
}

// ---------------- masked mean pooling ----------------
__global__ __launch_bounds__(512) void k_pool(const float* __restrict__ outm,
                                              const float* __restrict__ mask,
                                              float* __restrict__ pooled) {
    int b = blockIdx.x, tid = threadIdx.x;
    if (tid >= 500) return;
    float acc = 0.f, den = 0.f;
    for (int s = 0; s < S_; ++s) {
        float mk = mask[b * S_ + s];
        acc += outm[((size_t)(b * S_ + s)) * H_ + tid] * mk;
        den += mk;
    }
    pooled[b * H_ + tid] = acc / den;
}

// ---------------- session rep: sess[b,j,s,:] and avgd[b,j,s] ----------------
__global__ __launch_bounds__(512) void k_sess(const int* __restrict__ seqtim,
                                              const int* __restrict__ itemv,
                                              const int* __restrict__ histt,
                                              const int* __restrict__ histi,
                                              const float* __restrict__ timsim,
                                              const float* __restrict__ poid,
                                              const float* __restrict__ he,
                                              float* __restrict__ sess,
                                              float* __restrict__ avgd) {
    int bi = blockIdx.x;                // B*J*31
    int s = bi % 31;
    int tmpv = bi / 31;
    int j = tmpv & 3, b = tmpv >> 2;
    __shared__ float w[L_];
    __shared__ float pd[L_];
    __shared__ float stats[1];
    int tid = threadIdx.x;
    int st = seqtim[b * S_ + s];
    if (tid < L_) {
        int ht = histt[(b * J_ + j) * L_ + tid];
        w[tid] = timsim[st * NT_ + ht];
    }
    if (tid >= 64 && tid < 64 + L_) {   // parallel poi_dist gather
        int l = tid - 64;
        int iv = itemv[b * S_ + s];
        pd[l] = poid[(size_t)iv * NI_ + histi[(b * J_ + j) * L_ + l]];
    }
    __syncthreads();
    if (tid == 64) {
        float a = 0.f;
        for (int l = 0; l < L_; ++l) a += pd[l];
        avgd[(b * J_ + j) * 31 + s] = a * (1.f / 32.f);
    }
    if (tid == 0) {
        float m = -1e30f;
        for (int l = 0; l < L_; ++l) m = fmaxf(m, w[l]);
        float sm = 0.f;
        for (int l = 0; l < L_; ++l) { float e = expf(w[l] - m); w[l] = e; sm += e; }
        stats[0] = 1.f / sm;
    }
    __syncthreads();
    if (tid < 500) {
        float inv = stats[0];
        float acc = 0.f;
        const float* hp = he + ((size_t)(b * J_ * L_ + j * L_)) * H_ + tid;
        for (int l = 0; l < L_; ++l) acc += w[l] * inv * hp[(size_t)l * H_];
        sess[((size_t)((b * J_ + j) * 31 + s)) * H_ + tid] = acc;
    }
}

// ---------------- attention 1 ----------------
__global__ __launch_bounds__(512) void k_att1(const float* __restrict__ sess,
                                              const float* __restrict__ pooled,
                                              float* __restrict__ att1) {
    int bi = blockIdx.x;   // B*31
    int s = bi % 31, b = bi / 31;
    __shared__ float vec[H_];
    __shared__ float part[512];
    int tid = threadIdx.x;
    if (tid < 500) vec[tid] = pooled[b * H_ + tid];
    __syncthreads();
    int j = tid >> 7, i = tid & 127;
    const float* sp = sess + ((size_t)((b * J_ + j) * 31 + s)) * H_;
    float acc = 0.f;
    for (int h = i; h < H_; h += 128) acc += sp[h] * vec[h];
    part[tid] = acc;
    __syncthreads();
    for (int off = 64; off > 0; off >>= 1) {
        if (i < off) part[tid] += part[tid + off];
        __syncthreads();
    }
    float d0 = part[0], d1 = part[128], d2 = part[256], d3 = part[384];
    float m = fmaxf(fmaxf(d0, d1), fmaxf(d2, d3));
    float e0 = expf(d0 - m), e1 = expf(d1 - m), e2 = expf(d2 - m), e3 = expf(d3 - m);
    float inv = 1.f / (e0 + e1 + e2 + e3);
    if (tid < 500) {
        const float* s0 = sess + ((size_t)(b * J_ * 31 + s)) * H_ + tid;
        const size_t js = (size_t)31 * H_;
        float r = e0 * inv * s0[0] + e1 * inv * s0[js] + e2 * inv * s0[2 * js] + e3 * inv * s0[3 * js];
        att1[((size_t)(b * 31 + s)) * H_ + tid] = r;
    }
}

// ---------------- attention 2 ----------------
__global__ __launch_bounds__(512) void k_att2(const float* __restrict__ sess,
                                              const float* __restrict__ outy,
                                              const float* __restrict__ outm,
                                              const float* __restrict__ avgd,
                                              float* __restrict__ X) {
    int bi = blockIdx.x;   // B*31
    int s = bi % 31, b = bi / 31;
    __shared__ float vec[H_];
    __shared__ float part[512];
    int tid = threadIdx.x;
    if (tid < 500)
        vec[tid] = 0.5f * seluf(outy[((size_t)(b * 31 + s)) * H_ + tid]) +
                   0.5f * outm[((size_t)(b * S_ + s)) * H_ + tid];
    __syncthreads();
    int j = tid >> 7, i = tid & 127;
    const float* sp = sess + ((size_t)((b * J_ + j) * 31 + s)) * H_;
    float acc = 0.f;
    for (int h = i; h < H_; h += 128) acc += sp[h] * vec[h];
    part[tid] = acc;
    __syncthreads();
    for (int off = 64; off > 0; off >>= 1) {
        if (i < off) part[tid] += part[tid + off];
        __syncthreads();
    }
    float d0 = part[0]   / avgd[(b * J_ + 0) * 31 + s];
    float d1 = part[128] / avgd[(b * J_ + 1) * 31 + s];
    float d2 = part[256] / avgd[(b * J_ + 2) * 31 + s];
    float d3 = part[384] / avgd[(b * J_ + 3) * 31 + s];
    float m = fmaxf(fmaxf(d0, d1), fmaxf(d2, d3));
    float e0 = expf(d0 - m), e1 = expf(d1 - m), e2 = expf(d2 - m), e3 = expf(d3 - m);
    float inv = 1.f / (e0 + e1 + e2 + e3);
    if (tid < 500) {
        const float* s0 = sess + ((size_t)(b * J_ * 31 + s)) * H_ + tid;
        const size_t js = (size_t)31 * H_;
        float r = e0 * inv * s0[0] + e1 * inv * s0[js] + e2 * inv * s0[2 * js] + e3 * inv * s0[3 * js];
        X[((size_t)(b * S_ + s)) * 1000 + tid] = seluf(r);
    }
}

// ---------------- mix ----------------
__global__ __launch_bounds__(512) void k_mix(const float* __restrict__ outm,
                                             const float* __restrict__ outh,
                                             float* __restrict__ X) {
    int bs = blockIdx.x;   // B*S
    int tid = threadIdx.x;
    if (tid >= 500) return;
    size_t idx = (size_t)bs * H_ + tid;
    float om = 0.5f * (seluf(outm[idx]) + seluf(outh[idx]));
    X[(size_t)bs * 1000 + 500 + tid] = om;
    if ((bs & (S_ - 1)) == S_ - 1) X[(size_t)bs * 1000 + tid] = 0.f;
}

// ---------------- in-place log_softmax over rows of 5000 ----------------
__global__ __launch_bounds__(512) void k_lsm(float* __restrict__ out) {
    int row = blockIdx.x, tid = threadIdx.x;
    float* p = out + (size_t)row * NI_;
    __shared__ float red[512];
    float m = -1e30f;
    for (int i = tid; i < NI_; i += 512) m = fmaxf(m, p[i]);
    red[tid] = m;
    __syncthreads();
    for (int off = 256; off > 0; off >>= 1) {
        if (tid < off) red[tid] = fmaxf(red[tid], red[tid + off]);
        __syncthreads();
    }
    m = red[0];
    __syncthreads();
    float sm = 0.f;
    for (int i = tid; i < NI_; i += 512) sm += expf(p[i] - m);
    red[tid] = sm;
    __syncthreads();
    for (int off = 256; off > 0; off >>= 1) {
        if (tid < off) red[tid] += red[tid + off];
        __syncthreads();
    }
    float lse = m + logf(red[0]);
    __syncthreads();
    for (int i = tid; i < NI_; i += 512) p[i] -= lse;
}

extern "C" void kernel_launch(void* const* d_in, const int* in_sizes, int n_in,
                              void* d_out, int out_size, void* d_ws, size_t ws_size,
                              hipStream_t stream) {
    const int* item_vectors = (const int*)d_in[0];
    const int* sequence_tim = (const int*)d_in[1];
    const int* dilated_idx  = (const int*)d_in[2];
    const int* hist_items   = (const int*)d_in[3];
    const int* hist_tims    = (const int*)d_in[4];
    const float* mask       = (const float*)d_in[5];
    const float* tim_sim    = (const float*)d_in[6];
    const float* poi_dist   = (const float*)d_in[7];
    const float* emb_W      = (const float*)d_in[8];
    const float* lstm_Wi    = (const float*)d_in[9];
    const float* lstm_Wh    = (const float*)d_in[10];
    const float* lstm_b     = (const float*)d_in[11];
    const float* hist_Wi    = (const float*)d_in[12];
    const float* hist_Wh    = (const float*)d_in[13];
    const float* hist_b     = (const float*)d_in[14];
    const float* dil_Wi     = (const float*)d_in[15];
    const float* dil_Wh     = (const float*)d_in[16];
    const float* dil_b      = (const float*)d_in[17];
    const float* lin1_W     = (const float*)d_in[18];
    const float* lin1_b     = (const float*)d_in[19];
    const float* lin_W      = (const float*)d_in[20];
    const float* lin_b      = (const float*)d_in[21];
    float* out = (float*)d_out;
    float* ws  = (float*)d_ws;

    // workspace layout (float offsets)
    float* items   = ws + 0;        // 128000
    float* histemb = ws + 128000;   // 512000
    float* xwm     = ws + 640000;   // 512000
    float* xwd     = ws + 1152000;  // 512000
    float* xwh     = ws + 1664000;  // 2048000
    float* outm    = ws + 3712000;  // 128000
    float* outh    = ws + 3840000;  // 128000
    float* csg     = ws + 3968000;  // 128000
    float* he      = ws + 4096000;  // 512000
    float* pooled  = ws + 4608000;  // 4000
    float* sess    = ws + 4612000;  // 496000
    float* avgd    = ws + 5108000;  // 992
    float* att1    = ws + 5108992;  // 124000
    float* outy    = ws + 5232992;  // 124000
    float* Xbuf    = ws + 5356992;  // 256000
    int*   flags   = (int*)(ws + 5612992);  // 24 gangs * 16 slots * 32 pad = 12288 ints

    k_zero<<<dim3(48), dim3(256), 0, stream>>>(flags, 24 * 16 * FPAD_);
    k_embed<<<dim3(1280), dim3(128), 0, stream>>>(item_vectors, hist_items, emb_W, items, histemb);

    // input-side GEMMs with bias folded in
    k_gemm_bt<<<dim3(32, 4), dim3(256), 0, stream>>>(items, lstm_Wi, lstm_b, xwm, 256, G4_, E_);
    k_gemm_bt<<<dim3(32, 4), dim3(256), 0, stream>>>(items, dil_Wi, dil_b, xwd, 256, G4_, E_);
    k_gemm_bt<<<dim3(32, 16), dim3(256), 0, stream>>>(histemb, hist_Wi, hist_b, xwh, 1024, G4_, E_);

    k_rec9<<<dim3(256), dim3(256), 0, stream>>>(
        xwm, lstm_Wh, xwd, dil_Wh, dilated_idx, xwh, hist_Wh,
        outm, outh, csg, he, flags);

    k_pool<<<dim3(B_), dim3(512), 0, stream>>>(outm, mask, pooled);
    k_sess<<<dim3(B_ * J_ * 31), dim3(512), 0, stream>>>(sequence_tim, item_vectors, hist_tims,
                                                         hist_items, tim_sim, poi_dist, he, sess, avgd);
    k_att1<<<dim3(B_ * 31), dim3(512), 0, stream>>>(sess, pooled, att1);
    k_gemm_bt<<<dim3(8, 4), dim3(256), 0, stream>>>(att1, lin1_W, lin1_b, outy, 248, H_, H_);
    k_att2<<<dim3(B_ * 31), dim3(512), 0, stream>>>(sess, outy, outm, avgd, Xbuf);
    k_mix<<<dim3(B_ * S_), dim3(512), 0, stream>>>(outm, outh, Xbuf);

    k_gemm_bt<<<dim3(79, 4), dim3(256), 0, stream>>>(Xbuf, lin_W, lin_b, out, 256, NI_, 1000);
    k_lsm<<<dim3(256), dim3(512), 0, stream>>>(out);
}